// Round 1
// baseline (305.725 us; speedup 1.0000x reference)
//
#include <hip/hip_runtime.h>
#include <math.h>

#define B_N   131072
#define D_DIM 256
#define C_N   8
#define K_N   2
#define TAU_INV   10.0f     // 1/0.1
#define MARGIN_OV 0.3f
#define MARGIN_DIV 0.8f

// ---------------- Kernel 1: centers (tiny) ----------------
// One block, 256 threads. 16 centers x 256 dims.
// group g of 16 threads handles center ci = tid>>4.
__global__ __launch_bounds__(256) void centers_kernel(
    const float* __restrict__ centers,   // [C,K,D] = [16][256]
    float* __restrict__ cnorm_ws,        // [16][256] out
    float* __restrict__ out)             // scalar, pre-zeroed
{
    __shared__ float sCn[C_N * K_N][D_DIM];
    __shared__ float sRed[8];

    const int tid = threadIdx.x;
    const int ci  = tid >> 4;   // 0..15 center id
    const int g   = tid & 15;   // lane in 16-group

    // sum of squares for this center
    float ss = 0.f;
    for (int d = g; d < D_DIM; d += 16) {
        float v = centers[ci * D_DIM + d];
        ss += v * v;
    }
    // reduce within the 16-lane group (groups are 16-aligned inside the wave)
    #pragma unroll
    for (int m = 1; m < 16; m <<= 1) ss += __shfl_xor(ss, m, 64);

    const float inv = 1.0f / fmaxf(sqrtf(ss), 1e-12f);
    for (int d = g; d < D_DIM; d += 16) {
        float v = centers[ci * D_DIM + d] * inv;
        sCn[ci][d] = v;
        cnorm_ws[ci * D_DIM + d] = v;
    }
    __syncthreads();

    // pair (i,j): i = tid>>4, j = tid&15 ; full 16x16 ordered-pair matrix
    const int i = ci, j = g;
    float dot = 0.f;
    for (int d = 0; d < D_DIM; ++d) dot += sCn[i][d] * sCn[j][d];

    float ov = 0.f, dv = 0.f;
    const int icls = i / K_N, jcls = j / K_N;
    if (icls != jcls) {
        ov = fmaxf(dot - MARGIN_OV, 0.f);            // overlap: cross-class, all ordered pairs
    } else if (i < j) {
        dv = fmaxf(dot - MARGIN_DIV, 0.f);           // diversity: within-class p<q
    }

    #pragma unroll
    for (int m = 1; m < 64; m <<= 1) {
        ov += __shfl_xor(ov, m, 64);
        dv += __shfl_xor(dv, m, 64);
    }
    const int wave = tid >> 6, lane = tid & 63;
    if (lane == 0) { sRed[wave] = ov; sRed[4 + wave] = dv; }
    __syncthreads();
    if (tid == 0) {
        float ovs = sRed[0] + sRed[1] + sRed[2] + sRed[3];
        float dvs = sRed[4] + sRed[5] + sRed[6] + sRed[7];
        const float mask_sum = (float)(C_N * K_N * C_N * K_N - C_N * K_N * K_N); // 224
        const float div_cnt  = (float)(C_N * K_N * (K_N - 1) / 2);               // 8
        float L_ov = ovs / (mask_sum + 1e-6f);
        float L_dv = dvs / div_cnt;
        atomicAdd(out, 0.5f * L_ov + 0.5f * L_dv);
    }
}

// ---------------- Kernel 2: intra loss (HBM-bound) ----------------
// One wave per sample; 64 lanes x float4 = 256 dims, coalesced 1 KB row reads.
__global__ __launch_bounds__(256) void intra_kernel(
    const float* __restrict__ z,        // [B,D]
    const int*   __restrict__ labels,   // [B]
    const float* __restrict__ rel,      // [B]
    const float* __restrict__ radii,    // [C,K] raw (clip here)
    const float* __restrict__ cnorm,    // [16][256] from ws
    float* __restrict__ out)            // scalar, pre-zeroed
{
    const int lane   = threadIdx.x & 63;
    const int wave   = (blockIdx.x * blockDim.x + threadIdx.x) >> 6;
    const int nwaves = (gridDim.x * blockDim.x) >> 6;

    const float4* __restrict__ z4 = (const float4*)z;
    const float4* __restrict__ c4 = (const float4*)cnorm;

    float acc = 0.f;
    for (int s = wave; s < B_N; s += nwaves) {
        // wave-uniform label -> scalar center base address
        const int lbl = __builtin_amdgcn_readfirstlane(labels[s]);

        const float4 zv = z4[s * 64 + lane];
        const float4 c0 = c4[(lbl * 2 + 0) * 64 + lane];
        const float4 c1 = c4[(lbl * 2 + 1) * 64 + lane];

        float zz = zv.x * zv.x + zv.y * zv.y + zv.z * zv.z + zv.w * zv.w;
        float d0 = zv.x * c0.x + zv.y * c0.y + zv.z * c0.z + zv.w * c0.w;
        float d1 = zv.x * c1.x + zv.y * c1.y + zv.z * c1.z + zv.w * c1.w;

        #pragma unroll
        for (int m = 32; m >= 1; m >>= 1) {
            zz += __shfl_xor(zz, m, 64);
            d0 += __shfl_xor(d0, m, 64);
            d1 += __shfl_xor(d1, m, 64);
        }

        // epilogue: all lanes compute identically (no divergence)
        const float invn = 1.0f / fmaxf(sqrtf(zz), 1e-12f);
        const float s0 = d0 * invn;
        const float s1 = d1 * invn;
        const float r0 = fminf(fmaxf(fabsf(radii[lbl * 2 + 0]), 0.05f), 1.0f);
        const float r1 = fminf(fmaxf(fabsf(radii[lbl * 2 + 1]), 0.05f), 1.0f);
        // softmax over 2: q0 = 1/(1+e^{(s1-s0)/tau})
        const float q0 = 1.0f / (1.0f + __expf((s1 - s0) * TAU_INV));
        const float q1 = 1.0f - q0;
        const float val = q0 * ((1.0f - s0) - r0) + q1 * ((1.0f - s1) - r1);
        acc += rel[s] * fmaxf(val, 0.f);
    }

    if (lane == 0) atomicAdd(out, acc * (1.0f / (float)B_N));
}

extern "C" void kernel_launch(void* const* d_in, const int* in_sizes, int n_in,
                              void* d_out, int out_size, void* d_ws, size_t ws_size,
                              hipStream_t stream) {
    const float* z       = (const float*)d_in[0];
    const int*   labels  = (const int*)d_in[1];
    const float* rel     = (const float*)d_in[2];
    const float* centers = (const float*)d_in[3];
    const float* radii   = (const float*)d_in[4];
    float* out = (float*)d_out;
    float* cnorm_ws = (float*)d_ws;   // 16*256 floats = 16 KB

    // d_out is poisoned 0xAA before every call — zero it (memset node is capturable)
    hipMemsetAsync(out, 0, (size_t)out_size * sizeof(float), stream);

    centers_kernel<<<1, 256, 0, stream>>>(centers, cnorm_ws, out);

    // 2048 blocks * 4 waves = 8192 waves; 16 samples per wave, grid-stride
    intra_kernel<<<2048, 256, 0, stream>>>(z, labels, rel, radii, cnorm_ws, out);
}

// Round 2
// 198.430 us; speedup vs baseline: 1.5407x; 1.5407x over previous
//
#include <hip/hip_runtime.h>
#include <math.h>

#define B_N    131072
#define D_DIM  256
#define D4     64          // D/4
#define NC     16          // C*K
#define NBLK   2048        // B / (4 waves * 16 samples)
#define TAU_INV    10.0f
#define MARGIN_OV  0.3f
#define MARGIN_DIV 0.8f

// ---------------- Kernel 1: fused centers-normalize + intra partials ----------------
// 2048 blocks x 256 threads. Each block:
//   1. loads + normalizes the 16 centers into LDS (redundantly per block, ~16KB reads, L2-hot)
//   2. intra: each 16-lane group handles one sample; 4 samples/wave concurrent;
//      4 passes of float4 cover D=256; 4-stage butterfly reduction (xor 1,2,4,8)
//   3. block partial -> ws[blockIdx.x]  (no atomics)
// Block 0 additionally computes the overlap/diversity raw sums -> ws[2048], ws[2049].
__global__ __launch_bounds__(256) void fused_kernel(
    const float* __restrict__ z,        // [B,D]
    const int*   __restrict__ labels,   // [B]
    const float* __restrict__ rel,      // [B]
    const float* __restrict__ centers,  // [16,256] raw
    const float* __restrict__ radii,    // [16] raw
    float* __restrict__ ws)             // [2050] partials
{
    __shared__ float sC[NC * D_DIM];    // 16 KB normalized centers
    __shared__ float sRed[12];

    const int tid = threadIdx.x;

    // ---- 1. normalize centers: center ci handled by 16-lane group ----
    {
        const int ci = tid >> 4;        // 0..15
        const int gl = tid & 15;
        const float4* cr4 = (const float4*)centers;
        float4* sC4 = (float4*)sC;
        float4 cv[4];
        float ssq = 0.f;
        #pragma unroll
        for (int p = 0; p < 4; ++p) {
            cv[p] = cr4[ci * D4 + p * 16 + gl];
            ssq += cv[p].x*cv[p].x + cv[p].y*cv[p].y + cv[p].z*cv[p].z + cv[p].w*cv[p].w;
        }
        #pragma unroll
        for (int m = 1; m < 16; m <<= 1) ssq += __shfl_xor(ssq, m, 64);
        const float cinv = 1.0f / fmaxf(sqrtf(ssq), 1e-12f);
        #pragma unroll
        for (int p = 0; p < 4; ++p) {
            float4 v = cv[p];
            v.x *= cinv; v.y *= cinv; v.z *= cinv; v.w *= cinv;
            sC4[ci * D4 + p * 16 + gl] = v;
        }
    }
    __syncthreads();

    // ---- 2. intra: 16 lanes per sample, 4 samples per wave ----
    const int wv = (blockIdx.x << 2) + (tid >> 6);  // global wave id 0..8191
    const int l  = tid & 15;                        // lane within group
    const int g  = (tid >> 4) & 3;                  // group within wave
    const float4* z4  = (const float4*)z;
    const float4* sC4 = (const float4*)sC;

    float acc = 0.f;
    #pragma unroll
    for (int t = 0; t < 4; ++t) {
        const int s   = (wv << 4) + (t << 2) + g;   // sample id
        const int lbl = labels[s];

        float zz = 0.f, d0 = 0.f, d1 = 0.f;
        #pragma unroll
        for (int p = 0; p < 4; ++p) {
            const float4 zv = z4[s * D4 + p * 16 + l];
            const float4 a  = sC4[(lbl * 2 + 0) * D4 + p * 16 + l];
            const float4 b  = sC4[(lbl * 2 + 1) * D4 + p * 16 + l];
            zz += zv.x*zv.x + zv.y*zv.y + zv.z*zv.z + zv.w*zv.w;
            d0 += zv.x*a.x  + zv.y*a.y  + zv.z*a.z  + zv.w*a.w;
            d1 += zv.x*b.x  + zv.y*b.y  + zv.z*b.z  + zv.w*b.w;
        }
        // 4-stage butterfly within the 16-lane group (reduces 4 samples per instr)
        #pragma unroll
        for (int m = 1; m < 16; m <<= 1) {
            zz += __shfl_xor(zz, m, 64);
            d0 += __shfl_xor(d0, m, 64);
            d1 += __shfl_xor(d1, m, 64);
        }
        const float invn = 1.0f / fmaxf(sqrtf(zz), 1e-12f);
        const float s0 = d0 * invn;
        const float s1 = d1 * invn;
        const float r0 = fminf(fmaxf(fabsf(radii[lbl * 2 + 0]), 0.05f), 1.0f);
        const float r1 = fminf(fmaxf(fabsf(radii[lbl * 2 + 1]), 0.05f), 1.0f);
        const float q0 = 1.0f / (1.0f + __expf((s1 - s0) * TAU_INV));
        const float val = q0 * ((1.0f - s0) - r0) + (1.0f - q0) * ((1.0f - s1) - r1);
        // count each sample once (lane 0 of the group); cndmask, no divergence cost
        acc += (l == 0) ? rel[s] * fmaxf(val, 0.f) : 0.f;
    }

    // ---- 3. block 0 only: overlap + diversity raw sums from LDS centers ----
    float ovs = 0.f, dvs = 0.f;
    if (blockIdx.x == 0) {
        const int i = tid >> 4, j = tid & 15;   // all 256 ordered pairs
        float dot = 0.f;
        #pragma unroll 4
        for (int d = 0; d < D4; ++d) {
            const float4 a = sC4[i * D4 + d];
            const float4 b = sC4[j * D4 + d];
            dot += a.x*b.x + a.y*b.y + a.z*b.z + a.w*b.w;
        }
        if ((i >> 1) != (j >> 1))      ovs = fmaxf(dot - MARGIN_OV, 0.f);
        else if (i < j)                dvs = fmaxf(dot - MARGIN_DIV, 0.f);
    }

    // ---- block reduction (acc has nonzero only on l==0 lanes) ----
    #pragma unroll
    for (int m = 1; m < 64; m <<= 1) {
        acc += __shfl_xor(acc, m, 64);
        ovs += __shfl_xor(ovs, m, 64);
        dvs += __shfl_xor(dvs, m, 64);
    }
    const int w = tid >> 6;
    if ((tid & 63) == 0) { sRed[w] = acc; sRed[4 + w] = ovs; sRed[8 + w] = dvs; }
    __syncthreads();
    if (tid == 0) {
        ws[blockIdx.x] = sRed[0] + sRed[1] + sRed[2] + sRed[3];
        if (blockIdx.x == 0) {
            ws[NBLK + 0] = sRed[4] + sRed[5] + sRed[6] + sRed[7];
            ws[NBLK + 1] = sRed[8] + sRed[9] + sRed[10] + sRed[11];
        }
    }
}

// ---------------- Kernel 2: final reduce (tiny) ----------------
__global__ __launch_bounds__(256) void finalize_kernel(
    const float* __restrict__ ws, float* __restrict__ out)
{
    __shared__ float sRed[4];
    const int tid = threadIdx.x;
    float a = 0.f;
    #pragma unroll
    for (int k = 0; k < NBLK / 256; ++k) a += ws[tid + k * 256];
    #pragma unroll
    for (int m = 1; m < 64; m <<= 1) a += __shfl_xor(a, m, 64);
    if ((tid & 63) == 0) sRed[tid >> 6] = a;
    __syncthreads();
    if (tid == 0) {
        const float intra = (sRed[0] + sRed[1] + sRed[2] + sRed[3]) * (1.0f / (float)B_N);
        const float l_ov  = ws[NBLK + 0] / (224.0f + 1e-6f);   // mask_sum = 16*16 - 16*2
        const float l_dv  = ws[NBLK + 1] * (1.0f / 8.0f);      // C*K*(K-1)/2
        out[0] = intra + 0.5f * l_ov + 0.5f * l_dv;
    }
}

extern "C" void kernel_launch(void* const* d_in, const int* in_sizes, int n_in,
                              void* d_out, int out_size, void* d_ws, size_t ws_size,
                              hipStream_t stream) {
    const float* z       = (const float*)d_in[0];
    const int*   labels  = (const int*)d_in[1];
    const float* rel     = (const float*)d_in[2];
    const float* centers = (const float*)d_in[3];
    const float* radii   = (const float*)d_in[4];
    float* out = (float*)d_out;
    float* wsf = (float*)d_ws;   // 2050 floats used

    fused_kernel<<<NBLK, 256, 0, stream>>>(z, labels, rel, centers, radii, wsf);
    finalize_kernel<<<1, 256, 0, stream>>>(wsf, out);
}

// Round 3
// 198.144 us; speedup vs baseline: 1.5429x; 1.0014x over previous
//
#include <hip/hip_runtime.h>
#include <math.h>

#define B_N    131072
#define D_DIM  256
#define D4     64          // D/4 float4s per row
#define NC     16          // C*K centers
#define CPAD   65          // padded center row stride in float4 (260 floats; 16B aligned, staggers banks)
#define NBLK   2048        // B / (4 waves * 16 samples)
#define TAU_INV    10.0f
#define MARGIN_OV  0.3f
#define MARGIN_DIV 0.8f

// ---------------- Kernel 1: fused centers-normalize + intra partials ----------------
// 2048 blocks x 256 threads (4 waves). Per wave: 16 samples, 8 lanes/sample,
// 2 t-iterations of 8 concurrent samples. All global loads (labels, rel, radii,
// z) are issued before the prologue barrier so their latency hides under the
// center normalization.
__global__ __launch_bounds__(256) void fused_kernel(
    const float* __restrict__ z,        // [B,D]
    const int*   __restrict__ labels,   // [B]
    const float* __restrict__ rel,      // [B]
    const float* __restrict__ centers,  // [16,256] raw
    const float* __restrict__ radii,    // [16] raw
    float* __restrict__ ws)             // [2050] partials
{
    __shared__ float sC[NC * CPAD * 4]; // 16 centers x 260 floats (padded) ~16.6 KB
    __shared__ float sRed[12];

    const int tid = threadIdx.x;
    const int wv  = (blockIdx.x << 2) + (tid >> 6);  // global wave id 0..8191
    const int g   = (tid >> 3) & 7;                  // 8-lane group id in wave
    const int l   = tid & 7;                         // lane in group

    // ---- hoisted per-sample metadata loads (independent of LDS) ----
    const int sA = (wv << 4) + g;                    // t=0 sample
    const int sB = sA + 8;                           // t=1 sample
    const int lblA = labels[sA];
    const int lblB = labels[sB];
    const float relA = rel[sA];
    const float relB = rel[sB];
    const float rA0 = fminf(fmaxf(fabsf(radii[lblA * 2 + 0]), 0.05f), 1.0f);
    const float rA1 = fminf(fmaxf(fabsf(radii[lblA * 2 + 1]), 0.05f), 1.0f);
    const float rB0 = fminf(fmaxf(fabsf(radii[lblB * 2 + 0]), 0.05f), 1.0f);
    const float rB1 = fminf(fmaxf(fabsf(radii[lblB * 2 + 1]), 0.05f), 1.0f);

    // ---- prologue: normalize 16 centers into (padded) LDS; 16 lanes/center ----
    {
        const int ci = tid >> 4;        // 0..15
        const int gl = tid & 15;
        const float4* cr4 = (const float4*)centers;
        float4* sC4 = (float4*)sC;
        float4 cv[4];
        float ssq = 0.f;
        #pragma unroll
        for (int p = 0; p < 4; ++p) {
            cv[p] = cr4[ci * D4 + p * 16 + gl];
            ssq += cv[p].x*cv[p].x + cv[p].y*cv[p].y + cv[p].z*cv[p].z + cv[p].w*cv[p].w;
        }
        #pragma unroll
        for (int m = 1; m < 16; m <<= 1) ssq += __shfl_xor(ssq, m, 64);
        const float cinv = 1.0f / fmaxf(sqrtf(ssq), 1e-12f);
        #pragma unroll
        for (int p = 0; p < 4; ++p) {
            float4 v = cv[p];
            v.x *= cinv; v.y *= cinv; v.z *= cinv; v.w *= cinv;
            sC4[ci * CPAD + p * 16 + gl] = v;
        }
    }

    // ---- hoisted z loads: 8 float4 per sample-slot, both t-iters (global, long-latency) ----
    const float4* z4 = (const float4*)z;
    float4 zA[8], zB[8];
    #pragma unroll
    for (int p = 0; p < 8; ++p) zA[p] = z4[sA * D4 + p * 8 + l];
    #pragma unroll
    for (int p = 0; p < 8; ++p) zB[p] = z4[sB * D4 + p * 8 + l];

    __syncthreads();

    const float4* sC4 = (const float4*)sC;
    float acc = 0.f;

    // ---- t-iter A ----
    {
        float zz = 0.f, d0 = 0.f, d1 = 0.f;
        #pragma unroll
        for (int p = 0; p < 8; ++p) {
            const float4 zv = zA[p];
            const float4 a  = sC4[(lblA * 2 + 0) * CPAD + p * 8 + l];
            const float4 b  = sC4[(lblA * 2 + 1) * CPAD + p * 8 + l];
            zz += zv.x*zv.x + zv.y*zv.y + zv.z*zv.z + zv.w*zv.w;
            d0 += zv.x*a.x  + zv.y*a.y  + zv.z*a.z  + zv.w*a.w;
            d1 += zv.x*b.x  + zv.y*b.y  + zv.z*b.z  + zv.w*b.w;
        }
        #pragma unroll
        for (int m = 1; m < 8; m <<= 1) {   // 3 stages; masks 1,2 are DPP quad-perm
            zz += __shfl_xor(zz, m, 64);
            d0 += __shfl_xor(d0, m, 64);
            d1 += __shfl_xor(d1, m, 64);
        }
        const float invn = 1.0f / fmaxf(sqrtf(zz), 1e-12f);
        const float s0 = d0 * invn;
        const float s1 = d1 * invn;
        const float q0 = 1.0f / (1.0f + __expf((s1 - s0) * TAU_INV));
        const float val = q0 * ((1.0f - s0) - rA0) + (1.0f - q0) * ((1.0f - s1) - rA1);
        acc += (l == 0) ? relA * fmaxf(val, 0.f) : 0.f;
    }

    // ---- t-iter B ----
    {
        float zz = 0.f, d0 = 0.f, d1 = 0.f;
        #pragma unroll
        for (int p = 0; p < 8; ++p) {
            const float4 zv = zB[p];
            const float4 a  = sC4[(lblB * 2 + 0) * CPAD + p * 8 + l];
            const float4 b  = sC4[(lblB * 2 + 1) * CPAD + p * 8 + l];
            zz += zv.x*zv.x + zv.y*zv.y + zv.z*zv.z + zv.w*zv.w;
            d0 += zv.x*a.x  + zv.y*a.y  + zv.z*a.z  + zv.w*a.w;
            d1 += zv.x*b.x  + zv.y*b.y  + zv.z*b.z  + zv.w*b.w;
        }
        #pragma unroll
        for (int m = 1; m < 8; m <<= 1) {
            zz += __shfl_xor(zz, m, 64);
            d0 += __shfl_xor(d0, m, 64);
            d1 += __shfl_xor(d1, m, 64);
        }
        const float invn = 1.0f / fmaxf(sqrtf(zz), 1e-12f);
        const float s0 = d0 * invn;
        const float s1 = d1 * invn;
        const float q0 = 1.0f / (1.0f + __expf((s1 - s0) * TAU_INV));
        const float val = q0 * ((1.0f - s0) - rB0) + (1.0f - q0) * ((1.0f - s1) - rB1);
        acc += (l == 0) ? relB * fmaxf(val, 0.f) : 0.f;
    }

    // ---- block 0 only: overlap + diversity raw sums from LDS centers ----
    float ovs = 0.f, dvs = 0.f;
    if (blockIdx.x == 0) {
        const int i = tid >> 4, j = tid & 15;   // all 256 ordered pairs
        float dot = 0.f;
        #pragma unroll 4
        for (int d = 0; d < D4; ++d) {
            const float4 a = sC4[i * CPAD + d];
            const float4 b = sC4[j * CPAD + d];
            dot += a.x*b.x + a.y*b.y + a.z*b.z + a.w*b.w;
        }
        if ((i >> 1) != (j >> 1))      ovs = fmaxf(dot - MARGIN_OV, 0.f);
        else if (i < j)                dvs = fmaxf(dot - MARGIN_DIV, 0.f);
    }

    // ---- block reduction (acc nonzero only on l==0 lanes) ----
    #pragma unroll
    for (int m = 1; m < 64; m <<= 1) {
        acc += __shfl_xor(acc, m, 64);
        ovs += __shfl_xor(ovs, m, 64);
        dvs += __shfl_xor(dvs, m, 64);
    }
    const int w = tid >> 6;
    if ((tid & 63) == 0) { sRed[w] = acc; sRed[4 + w] = ovs; sRed[8 + w] = dvs; }
    __syncthreads();
    if (tid == 0) {
        ws[blockIdx.x] = sRed[0] + sRed[1] + sRed[2] + sRed[3];
        if (blockIdx.x == 0) {
            ws[NBLK + 0] = sRed[4] + sRed[5] + sRed[6] + sRed[7];
            ws[NBLK + 1] = sRed[8] + sRed[9] + sRed[10] + sRed[11];
        }
    }
}

// ---------------- Kernel 2: final reduce (tiny) ----------------
__global__ __launch_bounds__(256) void finalize_kernel(
    const float* __restrict__ ws, float* __restrict__ out)
{
    __shared__ float sRed[4];
    const int tid = threadIdx.x;
    float a = 0.f;
    #pragma unroll
    for (int k = 0; k < NBLK / 256; ++k) a += ws[tid + k * 256];
    #pragma unroll
    for (int m = 1; m < 64; m <<= 1) a += __shfl_xor(a, m, 64);
    if ((tid & 63) == 0) sRed[tid >> 6] = a;
    __syncthreads();
    if (tid == 0) {
        const float intra = (sRed[0] + sRed[1] + sRed[2] + sRed[3]) * (1.0f / (float)B_N);
        const float l_ov  = ws[NBLK + 0] / (224.0f + 1e-6f);   // mask_sum = 16*16 - 16*2
        const float l_dv  = ws[NBLK + 1] * (1.0f / 8.0f);      // C*K*(K-1)/2
        out[0] = intra + 0.5f * l_ov + 0.5f * l_dv;
    }
}

extern "C" void kernel_launch(void* const* d_in, const int* in_sizes, int n_in,
                              void* d_out, int out_size, void* d_ws, size_t ws_size,
                              hipStream_t stream) {
    const float* z       = (const float*)d_in[0];
    const int*   labels  = (const int*)d_in[1];
    const float* rel     = (const float*)d_in[2];
    const float* centers = (const float*)d_in[3];
    const float* radii   = (const float*)d_in[4];
    float* out = (float*)d_out;
    float* wsf = (float*)d_ws;   // 2050 floats used

    fused_kernel<<<NBLK, 256, 0, stream>>>(z, labels, rel, centers, radii, wsf);
    finalize_kernel<<<1, 256, 0, stream>>>(wsf, out);
}